// Round 1
// baseline (842.049 us; speedup 1.0000x reference)
//
#include <hip/hip_runtime.h>
#include <cmath>

typedef __bf16 bf16;
typedef __bf16 bf16x8 __attribute__((ext_vector_type(8)));
typedef __bf16 bf16x4v __attribute__((ext_vector_type(4)));
typedef float f32x4 __attribute__((ext_vector_type(4)));

#define DEV __device__ __forceinline__

// async global->LDS, 16B per lane. LDS dest = wave-uniform base + lane*16.
DEV void gld16(const void* g, void* l) {
  __builtin_amdgcn_global_load_lds((__attribute__((address_space(1))) void*)(g),
                                   (__attribute__((address_space(3))) void*)(l), 16, 0, 0);
}

DEV f32x4 mfma16(bf16x8 a, bf16x8 b, f32x4 c) {
  return __builtin_amdgcn_mfma_f32_16x16x32_bf16(a, b, c, 0, 0, 0);
}

// ---------------- LayerNorm: x fp32 [4096][768] -> h bf16 ----------------
__global__ __launch_bounds__(256) void ln_kernel(const float* __restrict__ x,
    const float* __restrict__ g, const float* __restrict__ be, bf16* __restrict__ h)
{
  const int row = blockIdx.x, t = threadIdx.x;
  const float* xr = x + (size_t)row * 768;
  float v0 = xr[t], v1 = xr[t + 256], v2 = xr[t + 512];
  float s = v0 + v1 + v2;
  float ss = v0 * v0 + v1 * v1 + v2 * v2;
#pragma unroll
  for (int m = 32; m >= 1; m >>= 1) { s += __shfl_xor(s, m); ss += __shfl_xor(ss, m); }
  __shared__ float ps[8];
  const int w = t >> 6;
  if ((t & 63) == 0) { ps[w] = s; ps[4 + w] = ss; }
  __syncthreads();
  s = ps[0] + ps[1] + ps[2] + ps[3];
  ss = ps[4] + ps[5] + ps[6] + ps[7];
  const float mu = s * (1.0f / 768.0f);
  const float var = ss * (1.0f / 768.0f) - mu * mu;
  const float rs = rsqrtf(var + 1e-5f);
  bf16* hr = h + (size_t)row * 768;
  hr[t]       = (bf16)((v0 - mu) * rs * g[t]       + be[t]);
  hr[t + 256] = (bf16)((v1 - mu) * rs * g[t + 256] + be[t + 256]);
  hr[t + 512] = (bf16)((v2 - mu) * rs * g[t + 512] + be[t + 512]);
}

// -------- weight transpose+convert: w fp32 [din][dout] -> wT bf16 [dout][din] --------
__global__ __launch_bounds__(256) void transpose_w(const float* __restrict__ w,
    bf16* __restrict__ wT, int din, int dout)
{
  __shared__ __align__(16) float tw[64 * 68];
  const int t = threadIdx.x;
  const int n0 = blockIdx.x * 64, k0 = blockIdx.y * 64;
#pragma unroll
  for (int it = 0; it < 4; ++it) {
    const int slot = it * 256 + t;
    const int r = slot >> 4, c = slot & 15;
    *(f32x4*)(tw + r * 68 + c * 4) = *(const f32x4*)(w + (size_t)(k0 + r) * dout + n0 + c * 4);
  }
  __syncthreads();
#pragma unroll
  for (int it = 0; it < 2; ++it) {
    const int slot = it * 256 + t;
    const int n = slot >> 3, c = slot & 7;
    bf16x8 o;
#pragma unroll
    for (int j = 0; j < 8; ++j) o[j] = (bf16)tw[(c * 8 + j) * 68 + n];
    *(bf16x8*)(wT + (size_t)(n0 + n) * din + k0 + c * 8) = o;
  }
}

// -------- v [bh][s][64] -> vT [bh][64][2048] (bf16) --------
__global__ __launch_bounds__(256) void transpose_v(const bf16* __restrict__ v, bf16* __restrict__ vT)
{
  __shared__ __align__(16) bf16 tv[64 * 80];
  const int t = threadIdx.x;
  const int s0 = blockIdx.x * 64, bh = blockIdx.y;
  const bf16* vg = v + ((size_t)bh * 2048 + s0) * 64;
#pragma unroll
  for (int it = 0; it < 2; ++it) {
    const int slot = it * 256 + t;
    const int r = slot >> 3, c = slot & 7;
    *(bf16x8*)(tv + r * 80 + c * 8) = *(const bf16x8*)(vg + slot * 8);
  }
  __syncthreads();
  bf16* og = vT + (size_t)bh * 64 * 2048 + s0;
#pragma unroll
  for (int it = 0; it < 2; ++it) {
    const int slot = it * 256 + t;
    const int d = slot >> 3, c = slot & 7;
    bf16x8 o;
#pragma unroll
    for (int j = 0; j < 8; ++j) o[j] = tv[(c * 8 + j) * 80 + d];
    *(bf16x8*)(og + (size_t)d * 2048 + c * 8) = o;
  }
}

// -------- GEMM C = A[M][K] * B[N][K]^T, 128x128 tile, BK=32, 256 thr --------
// MODE 0: QKV  (outb=q, kout=k, vout=v head-major, bias0/1/2 = bq/bk/bv)
// MODE 1: WO   (outf = resid + acc + bias0, ld 768)
// MODE 2: W1   (outb = bf16(gelu(acc+bias0)), ld 3072)
// MODE 3: W2   (outf = resid + acc + bias0, ld 768)
template <int MODE>
__global__ __launch_bounds__(256, 2) void gemm_bt(
    const bf16* __restrict__ A, const bf16* __restrict__ B, const int K,
    const float* __restrict__ bias0, const float* __restrict__ bias1,
    const float* __restrict__ bias2, const float* __restrict__ resid,
    float* __restrict__ outf, bf16* __restrict__ outb,
    bf16* __restrict__ kout, bf16* __restrict__ vout)
{
  __shared__ __align__(16) bf16 As[128 * 32];
  __shared__ __align__(16) bf16 Bs[128 * 32];
  const int t = threadIdx.x;
  const int m0 = blockIdx.y * 128, n0 = blockIdx.x * 128;
  const int w = t >> 6, lane = t & 63, l15 = lane & 15, quad = lane >> 4;
  const int wr = (w >> 1) * 64, wc = (w & 1) * 64;

  const f32x4 zero = {0.f, 0.f, 0.f, 0.f};
  f32x4 acc[4][4];
#pragma unroll
  for (int i = 0; i < 4; ++i)
#pragma unroll
    for (int j = 0; j < 4; ++j) acc[i][j] = zero;

  for (int k0 = 0; k0 < K; k0 += 32) {
#pragma unroll
    for (int j = 0; j < 2; ++j) {
      const int slot = j * 256 + t;
      const int row = slot >> 2, kc = slot & 3;
      gld16(A + (size_t)(m0 + row) * K + k0 + kc * 8, As + (size_t)(j * 256 + (t & 192)) * 8);
      gld16(B + (size_t)(n0 + row) * K + k0 + kc * 8, Bs + (size_t)(j * 256 + (t & 192)) * 8);
    }
    __syncthreads();
    bf16x8 af[4], bfr[4];
#pragma unroll
    for (int i = 0; i < 4; ++i) af[i] = *(const bf16x8*)(As + (wr + i * 16 + l15) * 32 + quad * 8);
#pragma unroll
    for (int i = 0; i < 4; ++i) bfr[i] = *(const bf16x8*)(Bs + (wc + i * 16 + l15) * 32 + quad * 8);
#pragma unroll
    for (int mi = 0; mi < 4; ++mi)
#pragma unroll
      for (int ni = 0; ni < 4; ++ni) acc[mi][ni] = mfma16(af[mi], bfr[ni], acc[mi][ni]);
    __syncthreads();
  }

  if constexpr (MODE == 0) {
    const int part = n0 / 768;
    const int cb = n0 - part * 768;
    const float* bp = part == 0 ? bias0 : (part == 1 ? bias1 : bias2);
    bf16* dst = part == 0 ? outb : (part == 1 ? kout : vout);
    float bias[4];
#pragma unroll
    for (int ni = 0; ni < 4; ++ni) bias[ni] = bp[cb + wc + ni * 16 + l15];
#pragma unroll
    for (int mi = 0; mi < 4; ++mi) {
      const int tok = m0 + wr + mi * 16 + quad * 4;
      const int b = tok >> 11, sIdx = tok & 2047;
#pragma unroll
      for (int ni = 0; ni < 4; ++ni) {
        const int c = cb + wc + ni * 16 + l15;
        const int head = c >> 6, d = c & 63;
        bf16* o = dst + (((size_t)b * 12 + head) * 2048 + sIdx) * 64 + d;
#pragma unroll
        for (int r = 0; r < 4; ++r) o[(size_t)r * 64] = (bf16)(acc[mi][ni][r] + bias[ni]);
      }
    }
  } else if constexpr (MODE == 1 || MODE == 3) {
    float bias[4];
#pragma unroll
    for (int ni = 0; ni < 4; ++ni) bias[ni] = bias0[n0 + wc + ni * 16 + l15];
#pragma unroll
    for (int mi = 0; mi < 4; ++mi) {
      const int row = m0 + wr + mi * 16 + quad * 4;
#pragma unroll
      for (int ni = 0; ni < 4; ++ni) {
        const int c = n0 + wc + ni * 16 + l15;
#pragma unroll
        for (int r = 0; r < 4; ++r) {
          const size_t idx = (size_t)(row + r) * 768 + c;
          outf[idx] = resid[idx] + acc[mi][ni][r] + bias[ni];
        }
      }
    }
  } else {  // MODE 2: gelu
    float bias[4];
#pragma unroll
    for (int ni = 0; ni < 4; ++ni) bias[ni] = bias0[n0 + wc + ni * 16 + l15];
#pragma unroll
    for (int mi = 0; mi < 4; ++mi) {
      const int row = m0 + wr + mi * 16 + quad * 4;
#pragma unroll
      for (int ni = 0; ni < 4; ++ni) {
        const int c = n0 + wc + ni * 16 + l15;
#pragma unroll
        for (int r = 0; r < 4; ++r) {
          const size_t idx = (size_t)(row + r) * 3072 + c;
          const float gv = acc[mi][ni][r] + bias[ni];
          outb[idx] = (bf16)(0.5f * gv * (1.0f + erff(gv * 0.70710678118f)));
        }
      }
    }
  }
}

// -------- attention: E = QK^T/8 (write fp32 to d_out slot), ctx = E*V --------
// grid (16 q-tiles, 24 bh), 256 thr. q-tile 128 rows, k-tile 64.
__global__ __launch_bounds__(256, 2) void attn_kernel(
    const bf16* __restrict__ q, const bf16* __restrict__ k,
    const bf16* __restrict__ vT, bf16* __restrict__ ctx,
    float* __restrict__ energy)
{
  __shared__ __align__(16) bf16 qs[128 * 64];
  __shared__ __align__(16) bf16 ks[64 * 64];
  __shared__ __align__(16) bf16 vs[64 * 64];
  __shared__ __align__(16) bf16 es[128 * 64];
  const int t = threadIdx.x, w = t >> 6, lane = t & 63;
  const int l15 = lane & 15, quad = lane >> 4;
  const int q0 = blockIdx.x * 128, bh = blockIdx.y;
  const int b = bh / 12, head = bh % 12;

  const bf16* qg = q + ((size_t)bh * 2048 + q0) * 64;
#pragma unroll
  for (int j = 0; j < 4; ++j) gld16(qg + (j * 256 + t) * 8, qs + (size_t)(j * 256 + (t & 192)) * 8);

  const f32x4 zero = {0.f, 0.f, 0.f, 0.f};
  f32x4 accc[2][4];
#pragma unroll
  for (int mi = 0; mi < 2; ++mi)
#pragma unroll
    for (int ni = 0; ni < 4; ++ni) accc[mi][ni] = zero;

  for (int kt = 0; kt < 32; ++kt) {
    const bf16* kg = k + ((size_t)bh * 2048 + kt * 64) * 64;
#pragma unroll
    for (int j = 0; j < 2; ++j) gld16(kg + (j * 256 + t) * 8, ks + (size_t)(j * 256 + (t & 192)) * 8);
    const bf16* vg = vT + (size_t)bh * 64 * 2048 + kt * 64;
#pragma unroll
    for (int j = 0; j < 2; ++j) {
      const int slot = j * 256 + t;
      const int d = slot >> 3, c = slot & 7;
      gld16(vg + (size_t)d * 2048 + c * 8, vs + (size_t)(j * 256 + (t & 192)) * 8);
    }
    __syncthreads();

    // E tile: rows (w*32..+32) x 64 cols
    f32x4 e[2][4];
#pragma unroll
    for (int mi = 0; mi < 2; ++mi)
#pragma unroll
      for (int nj = 0; nj < 4; ++nj) e[mi][nj] = zero;
#pragma unroll
    for (int kk = 0; kk < 2; ++kk) {
      bf16x8 aq[2];
#pragma unroll
      for (int mi = 0; mi < 2; ++mi)
        aq[mi] = *(const bf16x8*)(qs + (w * 32 + mi * 16 + l15) * 64 + kk * 32 + quad * 8);
#pragma unroll
      for (int nj = 0; nj < 4; ++nj) {
        bf16x8 kb8 = *(const bf16x8*)(ks + (nj * 16 + l15) * 64 + kk * 32 + quad * 8);
#pragma unroll
        for (int mi = 0; mi < 2; ++mi) e[mi][nj] = mfma16(aq[mi], kb8, e[mi][nj]);
      }
    }
    // scale 1/8, round to bf16 into es (A-layout round trip through LDS)
#pragma unroll
    for (int mi = 0; mi < 2; ++mi)
#pragma unroll
      for (int nj = 0; nj < 4; ++nj)
#pragma unroll
        for (int r = 0; r < 4; ++r)
          es[(w * 32 + mi * 16 + quad * 4 + r) * 64 + nj * 16 + l15] = (bf16)(e[mi][nj][r] * 0.125f);

    // copy this wave's band to global energy (fp32), coalesced
    float* eg = energy + ((size_t)(bh * 2048 + q0 + w * 32)) * 2048 + kt * 64;
#pragma unroll
    for (int it = 0; it < 8; ++it) {
      const int slot = it * 64 + lane;
      const int r = slot >> 4, c4 = slot & 15;
      bf16x4v ev = *(const bf16x4v*)(es + (w * 32 + r) * 64 + c4 * 4);
      f32x4 o = {(float)ev[0], (float)ev[1], (float)ev[2], (float)ev[3]};
      *(f32x4*)(eg + (size_t)r * 2048 + c4 * 4) = o;
    }

    // ctx += E_tile * V_tile
#pragma unroll
    for (int kk = 0; kk < 2; ++kk) {
      bf16x8 ae[2];
#pragma unroll
      for (int mi = 0; mi < 2; ++mi)
        ae[mi] = *(const bf16x8*)(es + (w * 32 + mi * 16 + l15) * 64 + kk * 32 + quad * 8);
#pragma unroll
      for (int ni = 0; ni < 4; ++ni) {
        bf16x8 vb8 = *(const bf16x8*)(vs + (ni * 16 + l15) * 64 + kk * 32 + quad * 8);
#pragma unroll
        for (int mi = 0; mi < 2; ++mi) accc[mi][ni] = mfma16(ae[mi], vb8, accc[mi][ni]);
      }
    }
    __syncthreads();
  }

  // ctx epilogue -> ctx[b*2048+s][head*64+d] bf16
#pragma unroll
  for (int mi = 0; mi < 2; ++mi) {
    const int srow = q0 + w * 32 + mi * 16 + quad * 4;
#pragma unroll
    for (int ni = 0; ni < 4; ++ni) {
      const int d = ni * 16 + l15;
      bf16* o = ctx + ((size_t)(b * 2048 + srow)) * 768 + head * 64 + d;
#pragma unroll
      for (int r = 0; r < 4; ++r) o[(size_t)r * 768] = (bf16)accc[mi][ni][r];
    }
  }
}

// -------- in-place softmax over energy rows (2048 wide), 1 wave per row --------
__global__ __launch_bounds__(256) void softmax_kernel(float* __restrict__ att)
{
  const int w = threadIdx.x >> 6, lane = threadIdx.x & 63;
  const size_t row = (size_t)blockIdx.x * 4 + w;
  float* p = att + row * 2048;
  f32x4 v[8];
  float s = 0.f;
#pragma unroll
  for (int c = 0; c < 8; ++c) {
    f32x4 x = *(const f32x4*)(p + c * 256 + lane * 4);
    f32x4 e = {__expf(x[0]), __expf(x[1]), __expf(x[2]), __expf(x[3])};
    v[c] = e;
    s += e[0] + e[1] + e[2] + e[3];
  }
#pragma unroll
  for (int m = 32; m >= 1; m >>= 1) s += __shfl_xor(s, m);
  const float inv = 1.0f / s;
#pragma unroll
  for (int c = 0; c < 8; ++c) {
    f32x4 o = {v[c][0] * inv, v[c][1] * inv, v[c][2] * inv, v[c][3] * inv};
    *(f32x4*)(p + c * 256 + lane * 4) = o;
  }
}

extern "C" void kernel_launch(void* const* d_in, const int* in_sizes, int n_in,
                              void* d_out, int out_size, void* d_ws, size_t ws_size,
                              hipStream_t stream)
{
  const float* x  = (const float*)d_in[0];
  const float* wq = (const float*)d_in[1];
  const float* bq = (const float*)d_in[2];
  const float* wk = (const float*)d_in[3];
  const float* bk = (const float*)d_in[4];
  const float* wv = (const float*)d_in[5];
  const float* bv = (const float*)d_in[6];
  const float* wo = (const float*)d_in[7];
  const float* bo = (const float*)d_in[8];
  const float* w1 = (const float*)d_in[9];
  const float* b1 = (const float*)d_in[10];
  const float* w2 = (const float*)d_in[11];
  const float* b2 = (const float*)d_in[12];
  const float* g1 = (const float*)d_in[13];
  const float* be1 = (const float*)d_in[14];
  const float* g2 = (const float*)d_in[15];
  const float* be2 = (const float*)d_in[16];

  float* out = (float*)d_out;
  float* energy = out + 3145728;  // attention slot doubles as energy scratch

  if (ws_size < (size_t)95944704) return;  // ws layout below needs ~91.5 MiB
  char* ws = (char*)d_ws;
  bf16* wqkvT = (bf16*)(ws + 0);          // 2304x768
  bf16* woT   = (bf16*)(ws + 3538944);    // 768x768
  bf16* w1T   = (bf16*)(ws + 4718592);    // 3072x768
  bf16* w2T   = (bf16*)(ws + 9437184);    // 768x3072
  bf16* h     = (bf16*)(ws + 14155776);   // 4096x768
  bf16* qb    = (bf16*)(ws + 20447232);   // 24x2048x64
  bf16* kb    = (bf16*)(ws + 26738688);
  bf16* vb    = (bf16*)(ws + 33030144);
  bf16* vTb   = (bf16*)(ws + 39321600);   // 24x64x2048
  bf16* ctxb  = (bf16*)(ws + 45613056);   // 4096x768
  float* x2   = (float*)(ws + 51904512);  // 4096x768 fp32
  bf16* h2    = (bf16*)(ws + 64487424);   // 4096x768
  bf16* a1    = (bf16*)(ws + 70778880);   // 4096x3072

  transpose_w<<<dim3(12, 12), 256, 0, stream>>>(wq, wqkvT, 768, 768);
  transpose_w<<<dim3(12, 12), 256, 0, stream>>>(wk, wqkvT + 768 * 768, 768, 768);
  transpose_w<<<dim3(12, 12), 256, 0, stream>>>(wv, wqkvT + 2 * 768 * 768, 768, 768);
  transpose_w<<<dim3(12, 12), 256, 0, stream>>>(wo, woT, 768, 768);
  transpose_w<<<dim3(48, 12), 256, 0, stream>>>(w1, w1T, 768, 3072);
  transpose_w<<<dim3(12, 48), 256, 0, stream>>>(w2, w2T, 3072, 768);

  ln_kernel<<<4096, 256, 0, stream>>>(x, g1, be1, h);
  gemm_bt<0><<<dim3(18, 32), 256, 0, stream>>>(h, wqkvT, 768, bq, bk, bv,
                                               nullptr, nullptr, qb, kb, vb);
  transpose_v<<<dim3(32, 24), 256, 0, stream>>>(vb, vTb);
  attn_kernel<<<dim3(16, 24), 256, 0, stream>>>(qb, kb, vTb, ctxb, energy);
  softmax_kernel<<<12288, 256, 0, stream>>>(energy);
  gemm_bt<1><<<dim3(6, 32), 256, 0, stream>>>(ctxb, woT, 768, bo, nullptr, nullptr,
                                              x, x2, nullptr, nullptr, nullptr);
  ln_kernel<<<4096, 256, 0, stream>>>(x2, g2, be2, h2);
  gemm_bt<2><<<dim3(24, 32), 256, 0, stream>>>(h2, w1T, 768, b1, nullptr, nullptr,
                                               nullptr, nullptr, a1, nullptr, nullptr);
  gemm_bt<3><<<dim3(6, 32), 256, 0, stream>>>(a1, w2T, 3072, b2, nullptr, nullptr,
                                              x2, out, nullptr, nullptr, nullptr);
}

// Round 2
// 732.409 us; speedup vs baseline: 1.1497x; 1.1497x over previous
//
#include <hip/hip_runtime.h>
#include <cmath>

typedef __bf16 bf16;
typedef __bf16 bf16x8 __attribute__((ext_vector_type(8)));
typedef __bf16 bf16x4v __attribute__((ext_vector_type(4)));
typedef float f32x4 __attribute__((ext_vector_type(4)));

#define DEV __device__ __forceinline__

// async global->LDS, 16B per lane. LDS dest = wave-uniform base + lane*16.
DEV void gld16(const void* g, void* l) {
  __builtin_amdgcn_global_load_lds((__attribute__((address_space(1))) void*)(g),
                                   (__attribute__((address_space(3))) void*)(l), 16, 0, 0);
}

DEV f32x4 mfma16(bf16x8 a, bf16x8 b, f32x4 c) {
  return __builtin_amdgcn_mfma_f32_16x16x32_bf16(a, b, c, 0, 0, 0);
}

// ---------------- LayerNorm: x fp32 [4096][768] -> h bf16 ----------------
__global__ __launch_bounds__(256) void ln_kernel(const float* __restrict__ x,
    const float* __restrict__ g, const float* __restrict__ be, bf16* __restrict__ h)
{
  const int row = blockIdx.x, t = threadIdx.x;
  const float* xr = x + (size_t)row * 768;
  float v0 = xr[t], v1 = xr[t + 256], v2 = xr[t + 512];
  float s = v0 + v1 + v2;
  float ss = v0 * v0 + v1 * v1 + v2 * v2;
#pragma unroll
  for (int m = 32; m >= 1; m >>= 1) { s += __shfl_xor(s, m); ss += __shfl_xor(ss, m); }
  __shared__ float ps[8];
  const int w = t >> 6;
  if ((t & 63) == 0) { ps[w] = s; ps[4 + w] = ss; }
  __syncthreads();
  s = ps[0] + ps[1] + ps[2] + ps[3];
  ss = ps[4] + ps[5] + ps[6] + ps[7];
  const float mu = s * (1.0f / 768.0f);
  const float var = ss * (1.0f / 768.0f) - mu * mu;
  const float rs = rsqrtf(var + 1e-5f);
  bf16* hr = h + (size_t)row * 768;
  hr[t]       = (bf16)((v0 - mu) * rs * g[t]       + be[t]);
  hr[t + 256] = (bf16)((v1 - mu) * rs * g[t + 256] + be[t + 256]);
  hr[t + 512] = (bf16)((v2 - mu) * rs * g[t + 512] + be[t + 512]);
}

// -------- weight transpose+convert: w fp32 [din][dout] -> wT bf16 [dout][din] --------
template <int DIN, int DOUT>
DEV void transpose_body(const float* __restrict__ w, bf16* __restrict__ wT,
                        int n0, int k0, int t)
{
  __shared__ __align__(16) float tw[64 * 68];
#pragma unroll
  for (int it = 0; it < 4; ++it) {
    const int slot = it * 256 + t;
    const int r = slot >> 4, c = slot & 15;
    *(f32x4*)(tw + r * 68 + c * 4) = *(const f32x4*)(w + (size_t)(k0 + r) * DOUT + n0 + c * 4);
  }
  __syncthreads();
#pragma unroll
  for (int it = 0; it < 2; ++it) {
    const int slot = it * 256 + t;
    const int n = slot >> 3, c = slot & 7;
    bf16x8 o;
#pragma unroll
    for (int j = 0; j < 8; ++j) o[j] = (bf16)tw[(c * 8 + j) * 68 + n];
    *(bf16x8*)(wT + (size_t)(n0 + n) * DIN + k0 + c * 8) = o;
  }
}

// four 768x768 weights in one launch (z selects source)
__global__ __launch_bounds__(256) void transpose_w4(
    const float* __restrict__ a, const float* __restrict__ b,
    const float* __restrict__ c, const float* __restrict__ d,
    bf16* __restrict__ qkvT, bf16* __restrict__ oT)
{
  const int z = blockIdx.z;
  const float* w = z == 0 ? a : (z == 1 ? b : (z == 2 ? c : d));
  bf16* dst = z < 3 ? qkvT + (size_t)z * 768 * 768 : oT;
  transpose_body<768, 768>(w, dst, blockIdx.x * 64, blockIdx.y * 64, threadIdx.x);
}

template <int DIN, int DOUT>
__global__ __launch_bounds__(256) void transpose_w(const float* __restrict__ w,
    bf16* __restrict__ wT)
{
  transpose_body<DIN, DOUT>(w, wT, blockIdx.x * 64, blockIdx.y * 64, threadIdx.x);
}

// -------- v [bh][s][64] -> vT [bh][64][2048] (bf16) --------
__global__ __launch_bounds__(256) void transpose_v(const bf16* __restrict__ v, bf16* __restrict__ vT)
{
  __shared__ __align__(16) bf16 tv[64 * 80];
  const int t = threadIdx.x;
  const int s0 = blockIdx.x * 64, bh = blockIdx.y;
  const bf16* vg = v + ((size_t)bh * 2048 + s0) * 64;
#pragma unroll
  for (int it = 0; it < 2; ++it) {
    const int slot = it * 256 + t;
    *(bf16x8*)(tv + (slot >> 3) * 80 + (slot & 7) * 8) = *(const bf16x8*)(vg + slot * 8);
  }
  __syncthreads();
  bf16* og = vT + (size_t)bh * 64 * 2048 + s0;
#pragma unroll
  for (int it = 0; it < 2; ++it) {
    const int slot = it * 256 + t;
    const int d = slot >> 3, c = slot & 7;
    bf16x8 o;
#pragma unroll
    for (int j = 0; j < 8; ++j) o[j] = tv[(c * 8 + j) * 80 + d];
    *(bf16x8*)(og + (size_t)d * 2048 + c * 8) = o;
  }
}

// -------- GEMM C = A[M][Kstride] * B[N][Kstride]^T, 128x128 tile, BK=32 --------
// MODE 0: QKV  (outb=q, kout=k, vout=v head-major, bias0/1/2 = bq/bk/bv)
// MODE 1/3: outf = resid + acc + bias0 (ld 768)
// MODE 2: outb = bf16(gelu(acc+bias0)) (ld 3072)
// MODE 4: split-K partial; blockIdx.z selects K slice; outf += z*3145728
template <int MODE>
__global__ __launch_bounds__(256, 2) void gemm_bt(
    const bf16* __restrict__ A, const bf16* __restrict__ B,
    const int K, const int Kstride,
    const float* __restrict__ bias0, const float* __restrict__ bias1,
    const float* __restrict__ bias2, const float* __restrict__ resid,
    float* __restrict__ outf, bf16* __restrict__ outb,
    bf16* __restrict__ kout, bf16* __restrict__ vout)
{
  __shared__ __align__(16) bf16 As[128 * 32];
  __shared__ __align__(16) bf16 Bs[128 * 32];
  const int t = threadIdx.x;
  const int m0 = blockIdx.y * 128, n0 = blockIdx.x * 128;
  const int kOff = (MODE == 4) ? blockIdx.z * K : 0;
  const int w = t >> 6, lane = t & 63, l15 = lane & 15, quad = lane >> 4;
  const int wr = (w >> 1) * 64, wc = (w & 1) * 64;

  const f32x4 zero = {0.f, 0.f, 0.f, 0.f};
  f32x4 acc[4][4];
#pragma unroll
  for (int i = 0; i < 4; ++i)
#pragma unroll
    for (int j = 0; j < 4; ++j) acc[i][j] = zero;

  for (int k0 = 0; k0 < K; k0 += 32) {
#pragma unroll
    for (int j = 0; j < 2; ++j) {
      const int slot = j * 256 + t;
      const int row = slot >> 2, kc = slot & 3;
      gld16(A + (size_t)(m0 + row) * Kstride + kOff + k0 + kc * 8,
            As + (size_t)(j * 256 + (t & 192)) * 8);
      gld16(B + (size_t)(n0 + row) * Kstride + kOff + k0 + kc * 8,
            Bs + (size_t)(j * 256 + (t & 192)) * 8);
    }
    __syncthreads();
    bf16x8 af[4], bfr[4];
#pragma unroll
    for (int i = 0; i < 4; ++i) af[i] = *(const bf16x8*)(As + (wr + i * 16 + l15) * 32 + quad * 8);
#pragma unroll
    for (int i = 0; i < 4; ++i) bfr[i] = *(const bf16x8*)(Bs + (wc + i * 16 + l15) * 32 + quad * 8);
#pragma unroll
    for (int mi = 0; mi < 4; ++mi)
#pragma unroll
      for (int ni = 0; ni < 4; ++ni) acc[mi][ni] = mfma16(af[mi], bfr[ni], acc[mi][ni]);
    __syncthreads();
  }

  if constexpr (MODE == 0) {
    const int part = n0 / 768;
    const int cb = n0 - part * 768;
    const float* bp = part == 0 ? bias0 : (part == 1 ? bias1 : bias2);
    bf16* dst = part == 0 ? outb : (part == 1 ? kout : vout);
    float bias[4];
#pragma unroll
    for (int ni = 0; ni < 4; ++ni) bias[ni] = bp[cb + wc + ni * 16 + l15];
#pragma unroll
    for (int mi = 0; mi < 4; ++mi) {
      const int tok = m0 + wr + mi * 16 + quad * 4;
      const int b = tok >> 11, sIdx = tok & 2047;
#pragma unroll
      for (int ni = 0; ni < 4; ++ni) {
        const int c = cb + wc + ni * 16 + l15;
        const int head = c >> 6, d = c & 63;
        bf16* o = dst + (((size_t)b * 12 + head) * 2048 + sIdx) * 64 + d;
#pragma unroll
        for (int r = 0; r < 4; ++r) o[(size_t)r * 64] = (bf16)(acc[mi][ni][r] + bias[ni]);
      }
    }
  } else if constexpr (MODE == 1 || MODE == 3) {
    float bias[4];
#pragma unroll
    for (int ni = 0; ni < 4; ++ni) bias[ni] = bias0[n0 + wc + ni * 16 + l15];
#pragma unroll
    for (int mi = 0; mi < 4; ++mi) {
      const int row = m0 + wr + mi * 16 + quad * 4;
#pragma unroll
      for (int ni = 0; ni < 4; ++ni) {
        const int c = n0 + wc + ni * 16 + l15;
#pragma unroll
        for (int r = 0; r < 4; ++r) {
          const size_t idx = (size_t)(row + r) * 768 + c;
          outf[idx] = resid[idx] + acc[mi][ni][r] + bias[ni];
        }
      }
    }
  } else if constexpr (MODE == 2) {
    float bias[4];
#pragma unroll
    for (int ni = 0; ni < 4; ++ni) bias[ni] = bias0[n0 + wc + ni * 16 + l15];
#pragma unroll
    for (int mi = 0; mi < 4; ++mi) {
      const int row = m0 + wr + mi * 16 + quad * 4;
#pragma unroll
      for (int ni = 0; ni < 4; ++ni) {
        const int c = n0 + wc + ni * 16 + l15;
#pragma unroll
        for (int r = 0; r < 4; ++r) {
          const size_t idx = (size_t)(row + r) * 3072 + c;
          const float gv = acc[mi][ni][r] + bias[ni];
          outb[idx] = (bf16)(0.5f * gv * (1.0f + erff(gv * 0.70710678118f)));
        }
      }
    }
  } else {  // MODE 4: raw partial
    float* op = outf + (size_t)blockIdx.z * 3145728;
#pragma unroll
    for (int mi = 0; mi < 4; ++mi) {
      const int row = m0 + wr + mi * 16 + quad * 4;
#pragma unroll
      for (int ni = 0; ni < 4; ++ni) {
        const int c = n0 + wc + ni * 16 + l15;
#pragma unroll
        for (int r = 0; r < 4; ++r) op[(size_t)(row + r) * 768 + c] = acc[mi][ni][r];
      }
    }
  }
}

// -------- split-K reduce: out = resid + p0 + p1 + bias --------
__global__ __launch_bounds__(256) void reduce_w2(const float* __restrict__ p0,
    const float* __restrict__ p1, const float* __restrict__ resid,
    const float* __restrict__ bias, float* __restrict__ out)
{
  const size_t i = ((size_t)blockIdx.x * 256 + threadIdx.x) * 4;
  f32x4 a = *(const f32x4*)(p0 + i);
  f32x4 b = *(const f32x4*)(p1 + i);
  f32x4 r = *(const f32x4*)(resid + i);
  f32x4 bb = *(const f32x4*)(bias + (i & 767));
  f32x4 o = {r[0] + a[0] + b[0] + bb[0], r[1] + a[1] + b[1] + bb[1],
             r[2] + a[2] + b[2] + bb[2], r[3] + a[3] + b[3] + bb[3]};
  *(f32x4*)(out + i) = o;
}

// -------- fused attention: ctx = (QK^T/8)V  AND  att = softmax(QK^T/8) --------
// Phase A: kt loop — E tiles (bf16-rounded), exp row-sum accumulation, ctx MFMA.
// Phase B: kt loop — recompute E tiles (identical bf16 rounding), write exp*inv.
// grid (16 q-tiles, 24 bh), 256 thr; q-tile 128 rows, k-tile 64.
__global__ __launch_bounds__(256, 2) void attn_kernel(
    const bf16* __restrict__ q, const bf16* __restrict__ k,
    const bf16* __restrict__ vT, bf16* __restrict__ ctx,
    float* __restrict__ att)
{
  __shared__ __align__(16) bf16 qs[128 * 64];
  __shared__ __align__(16) bf16 ks[64 * 64];
  __shared__ __align__(16) bf16 vs[64 * 64];
  __shared__ __align__(16) bf16 es[128 * 64];
  __shared__ float rsum[128];
  const int t = threadIdx.x, w = t >> 6, lane = t & 63;
  const int l15 = lane & 15, quad = lane >> 4;
  const int q0 = blockIdx.x * 128, bh = blockIdx.y;
  const int b = bh / 12, head = bh % 12;

  const bf16* qg = q + ((size_t)bh * 2048 + q0) * 64;
#pragma unroll
  for (int j = 0; j < 4; ++j) gld16(qg + (j * 256 + t) * 8, qs + (size_t)(j * 256 + (t & 192)) * 8);

  const f32x4 zero = {0.f, 0.f, 0.f, 0.f};
  f32x4 accc[2][4];
  float psum[2][4];
#pragma unroll
  for (int mi = 0; mi < 2; ++mi)
#pragma unroll
    for (int ni = 0; ni < 4; ++ni) { accc[mi][ni] = zero; psum[mi][ni] = 0.f; }

  for (int kt = 0; kt < 32; ++kt) {
    const bf16* kg = k + ((size_t)bh * 2048 + kt * 64) * 64;
#pragma unroll
    for (int j = 0; j < 2; ++j) gld16(kg + (j * 256 + t) * 8, ks + (size_t)(j * 256 + (t & 192)) * 8);
    const bf16* vg = vT + (size_t)bh * 64 * 2048 + kt * 64;
#pragma unroll
    for (int j = 0; j < 2; ++j) {
      const int slot = j * 256 + t;
      gld16(vg + (size_t)(slot >> 3) * 2048 + (slot & 7) * 8, vs + (size_t)(j * 256 + (t & 192)) * 8);
    }
    __syncthreads();

    f32x4 e[2][4];
#pragma unroll
    for (int mi = 0; mi < 2; ++mi)
#pragma unroll
      for (int nj = 0; nj < 4; ++nj) e[mi][nj] = zero;
#pragma unroll
    for (int kk = 0; kk < 2; ++kk) {
      bf16x8 aq[2];
#pragma unroll
      for (int mi = 0; mi < 2; ++mi)
        aq[mi] = *(const bf16x8*)(qs + (w * 32 + mi * 16 + l15) * 64 + kk * 32 + quad * 8);
#pragma unroll
      for (int nj = 0; nj < 4; ++nj) {
        bf16x8 kb8 = *(const bf16x8*)(ks + (nj * 16 + l15) * 64 + kk * 32 + quad * 8);
#pragma unroll
        for (int mi = 0; mi < 2; ++mi) e[mi][nj] = mfma16(aq[mi], kb8, e[mi][nj]);
      }
    }
    // round to bf16 into es (A-layout round trip) + accumulate exp row-sums
#pragma unroll
    for (int mi = 0; mi < 2; ++mi)
#pragma unroll
      for (int nj = 0; nj < 4; ++nj)
#pragma unroll
        for (int r = 0; r < 4; ++r) {
          const bf16 eb = (bf16)(e[mi][nj][r] * 0.125f);
          es[(w * 32 + mi * 16 + quad * 4 + r) * 64 + nj * 16 + l15] = eb;
          psum[mi][r] += __expf((float)eb);
        }

    // ctx += E_tile * V_tile
#pragma unroll
    for (int kk = 0; kk < 2; ++kk) {
      bf16x8 ae[2];
#pragma unroll
      for (int mi = 0; mi < 2; ++mi)
        ae[mi] = *(const bf16x8*)(es + (w * 32 + mi * 16 + l15) * 64 + kk * 32 + quad * 8);
#pragma unroll
      for (int ni = 0; ni < 4; ++ni) {
        bf16x8 vb8 = *(const bf16x8*)(vs + (ni * 16 + l15) * 64 + kk * 32 + quad * 8);
#pragma unroll
        for (int mi = 0; mi < 2; ++mi) accc[mi][ni] = mfma16(ae[mi], vb8, accc[mi][ni]);
      }
    }
    __syncthreads();
  }

  // finalize row sums (reduce across the 16-lane col group)
#pragma unroll
  for (int mi = 0; mi < 2; ++mi)
#pragma unroll
    for (int r = 0; r < 4; ++r) {
      float s = psum[mi][r];
#pragma unroll
      for (int m = 8; m >= 1; m >>= 1) s += __shfl_xor(s, m);
      if (l15 == 0) rsum[w * 32 + mi * 16 + quad * 4 + r] = s;
    }
  __syncthreads();

  // ctx epilogue -> ctx[b*2048+s][head*64+d] bf16
#pragma unroll
  for (int mi = 0; mi < 2; ++mi) {
    const int srow = q0 + w * 32 + mi * 16 + quad * 4;
#pragma unroll
    for (int ni = 0; ni < 4; ++ni) {
      const int d = ni * 16 + l15;
      bf16* o = ctx + ((size_t)(b * 2048 + srow)) * 768 + head * 64 + d;
#pragma unroll
      for (int r = 0; r < 4; ++r) o[(size_t)r * 768] = (bf16)accc[mi][ni][r];
    }
  }

  // Phase B: recompute E, write att = exp(E)/rowsum
  float inv[8];
#pragma unroll
  for (int it = 0; it < 8; ++it) inv[it] = 1.0f / rsum[w * 32 + it * 4 + quad];

  for (int kt = 0; kt < 32; ++kt) {
    const bf16* kg = k + ((size_t)bh * 2048 + kt * 64) * 64;
#pragma unroll
    for (int j = 0; j < 2; ++j) gld16(kg + (j * 256 + t) * 8, ks + (size_t)(j * 256 + (t & 192)) * 8);
    __syncthreads();

    f32x4 e[2][4];
#pragma unroll
    for (int mi = 0; mi < 2; ++mi)
#pragma unroll
      for (int nj = 0; nj < 4; ++nj) e[mi][nj] = zero;
#pragma unroll
    for (int kk = 0; kk < 2; ++kk) {
      bf16x8 aq[2];
#pragma unroll
      for (int mi = 0; mi < 2; ++mi)
        aq[mi] = *(const bf16x8*)(qs + (w * 32 + mi * 16 + l15) * 64 + kk * 32 + quad * 8);
#pragma unroll
      for (int nj = 0; nj < 4; ++nj) {
        bf16x8 kb8 = *(const bf16x8*)(ks + (nj * 16 + l15) * 64 + kk * 32 + quad * 8);
#pragma unroll
        for (int mi = 0; mi < 2; ++mi) e[mi][nj] = mfma16(aq[mi], kb8, e[mi][nj]);
      }
    }
#pragma unroll
    for (int mi = 0; mi < 2; ++mi)
#pragma unroll
      for (int nj = 0; nj < 4; ++nj)
#pragma unroll
        for (int r = 0; r < 4; ++r)
          es[(w * 32 + mi * 16 + quad * 4 + r) * 64 + nj * 16 + l15] = (bf16)(e[mi][nj][r] * 0.125f);

    float* eg = att + ((size_t)(bh * 2048 + q0 + w * 32)) * 2048 + kt * 64;
#pragma unroll
    for (int it = 0; it < 8; ++it) {
      const int slot = it * 64 + lane;
      const int r = slot >> 4, c4 = slot & 15;
      bf16x4v ev = *(const bf16x4v*)(es + (w * 32 + r) * 64 + c4 * 4);
      f32x4 o = {__expf((float)ev[0]) * inv[it], __expf((float)ev[1]) * inv[it],
                 __expf((float)ev[2]) * inv[it], __expf((float)ev[3]) * inv[it]};
      *(f32x4*)(eg + (size_t)r * 2048 + c4 * 4) = o;
    }
    __syncthreads();
  }
}

extern "C" void kernel_launch(void* const* d_in, const int* in_sizes, int n_in,
                              void* d_out, int out_size, void* d_ws, size_t ws_size,
                              hipStream_t stream)
{
  const float* x  = (const float*)d_in[0];
  const float* wq = (const float*)d_in[1];
  const float* bq = (const float*)d_in[2];
  const float* wk = (const float*)d_in[3];
  const float* bk = (const float*)d_in[4];
  const float* wv = (const float*)d_in[5];
  const float* bv = (const float*)d_in[6];
  const float* wo = (const float*)d_in[7];
  const float* bo = (const float*)d_in[8];
  const float* w1 = (const float*)d_in[9];
  const float* b1 = (const float*)d_in[10];
  const float* w2 = (const float*)d_in[11];
  const float* b2 = (const float*)d_in[12];
  const float* g1 = (const float*)d_in[13];
  const float* be1 = (const float*)d_in[14];
  const float* g2 = (const float*)d_in[15];
  const float* be2 = (const float*)d_in[16];

  float* out = (float*)d_out;
  float* att = out + 3145728;

  if (ws_size < (size_t)95944704) return;
  char* ws = (char*)d_ws;
  bf16* wqkvT = (bf16*)(ws + 0);          // 2304x768
  bf16* woT   = (bf16*)(ws + 3538944);    // 768x768
  bf16* w1T   = (bf16*)(ws + 4718592);    // 3072x768
  bf16* w2T   = (bf16*)(ws + 9437184);    // 768x3072
  bf16* h     = (bf16*)(ws + 14155776);   // 4096x768
  bf16* qb    = (bf16*)(ws + 20447232);   // 24x2048x64
  bf16* kb    = (bf16*)(ws + 26738688);
  bf16* vb    = (bf16*)(ws + 33030144);
  bf16* vTb   = (bf16*)(ws + 39321600);   // 24x64x2048
  bf16* ctxb  = (bf16*)(ws + 45613056);   // 4096x768
  float* x2   = (float*)(ws + 51904512);  // 4096x768 fp32
  bf16* h2    = (bf16*)(ws + 64487424);   // 4096x768
  bf16* a1    = (bf16*)(ws + 70778880);   // 4096x3072
  // W2 split-K partials reuse dead q/k region (qb onward, 25.2 MB available)
  float* w2p  = (float*)(ws + 20447232);  // 2 x 4096x768 fp32

  transpose_w4<<<dim3(12, 12, 4), 256, 0, stream>>>(wq, wk, wv, wo, wqkvT, woT);
  transpose_w<768, 3072><<<dim3(48, 12), 256, 0, stream>>>(w1, w1T);
  transpose_w<3072, 768><<<dim3(12, 48), 256, 0, stream>>>(w2, w2T);

  ln_kernel<<<4096, 256, 0, stream>>>(x, g1, be1, h);
  gemm_bt<0><<<dim3(18, 32), 256, 0, stream>>>(h, wqkvT, 768, 768, bq, bk, bv,
                                               nullptr, nullptr, qb, kb, vb);
  transpose_v<<<dim3(32, 24), 256, 0, stream>>>(vb, vTb);
  attn_kernel<<<dim3(16, 24), 256, 0, stream>>>(qb, kb, vTb, ctxb, att);
  gemm_bt<1><<<dim3(6, 32), 256, 0, stream>>>(ctxb, woT, 768, 768, bo, nullptr, nullptr,
                                              x, x2, nullptr, nullptr, nullptr);
  ln_kernel<<<4096, 256, 0, stream>>>(x2, g2, be2, h2);
  gemm_bt<2><<<dim3(24, 32), 256, 0, stream>>>(h2, w1T, 768, 768, b1, nullptr, nullptr,
                                               nullptr, nullptr, a1, nullptr, nullptr);
  gemm_bt<4><<<dim3(6, 32, 2), 256, 0, stream>>>(a1, w2T, 1536, 3072, nullptr, nullptr,
                                                 nullptr, nullptr, w2p, nullptr, nullptr, nullptr);
  reduce_w2<<<3072, 256, 0, stream>>>(w2p, w2p + 3145728, x2, b2, out);
}